// Round 14
// baseline (65.671 us; speedup 1.0000x reference)
//
#include <hip/hip_runtime.h>

#define EPS 1e-8f

__device__ __forceinline__ float sigmoidf_(float x) {
    return 1.0f / (1.0f + expf(-x));
}

// ---------------------------------------------------------------------------
// Single-kernel fused chunked scan, block-local carry exchange.
// Block = CPB chains x C chunks (length L). Thread (chain, chunk):
//   phase A: scan own chunk with zero carry into registers m[L] (kept live),
//            write aggregate to LDS agg[C][CPB].   (one __syncthreads)
//   phase B: Horner-combine own carry-in from s0 + agg[0..chunk) (uniform-j
//            LDS reads = broadcast; predicated; arithmetic identical to the
//            proven sequential pass), re-scan from REGISTERS (mag read once!),
//            normalize, store.
// No grid sync, no global S traffic, one launch: compulsory HBM only.
// ---------------------------------------------------------------------------

template <int CPB, int L, int C>
__global__ __launch_bounds__(CPB * C)
void fns14_fused(const float* __restrict__ mag,
                 const float* __restrict__ s0,
                 const float* __restrict__ weights,
                 const float* __restrict__ bias,
                 const float* __restrict__ alpha,
                 float* __restrict__ out,
                 int B, int T, int F) {
    __shared__ float agg[C][CPB];

    const int chainL = threadIdx.x % CPB;      // chain within block
    const int chunk  = threadIdx.x / CPB;      // time chunk
    const int bf = blockIdx.x * CPB + chainL;  // BF % CPB == 0 (checked host)
    const int b  = bf / F;
    const int f  = bf - b * F;

    const float a   = sigmoidf_(alpha[f]);
    const float oma = 1.0f - a;

    const float* p = mag + ((size_t)b * T + (size_t)chunk * L) * F + f;

    // ---- phase A: deep prefetch + zero-carry local scan ----
    float m[L];
#pragma unroll
    for (int t = 0; t < L; ++t)
        m[t] = p[(size_t)t * F];
    asm volatile("" ::: "memory");   // pin loads: all L in flight

    float local = 0.0f;
#pragma unroll
    for (int t = 0; t < L; ++t)
        local = local * oma + (m[t] * m[t]) * a;   // exact reference form

    agg[chunk][chainL] = local;
    __syncthreads();

    // ---- phase B: carry-in via Horner over LDS aggregates ----
    float D = 1.0f;                  // (1-a)^L via product
#pragma unroll
    for (int i = 0; i < L; ++i) D *= oma;

    float carry = s0[bf];
#pragma unroll
    for (int j = 0; j < C - 1; ++j) {
        float Sv = agg[j][chainL];   // uniform j: broadcast, conflict-free
        carry = (j < chunk) ? (carry * D + Sv) : carry;
    }

    const float w  = weights[f];
    const float bi = bias[f];
    float* o = out + ((size_t)b * T + (size_t)chunk * L) * F + f;

    // ---- re-scan from registers + normalize + store ----
#pragma unroll
    for (int t = 0; t < L; ++t) {
        carry = carry * oma + (m[t] * m[t]) * a;
        // 1/(sqrt+eps) via hw rcp (~1 ulp); bounded output -> abs err ~1e-6
        o[(size_t)t * F] = m[t] * __builtin_amdgcn_rcpf(sqrtf(carry) + EPS) * w + bi;
    }
}

// ---------------------------------------------------------------------------
// Proven R12 two-kernel path (fallback for other shapes).
// ---------------------------------------------------------------------------

template <int L>
__global__ __launch_bounds__(256)
void fns12_aggregate(const float* __restrict__ mag,
                     const float* __restrict__ alpha,
                     float* __restrict__ S,   // [C-1][BF]
                     int B, int T, int F, int C1) {
    const int BF = B * F;
    int g = blockIdx.x * blockDim.x + threadIdx.x;
    if (g >= BF * C1) return;
    const int bf = g % BF;
    const int c  = g / BF;
    const int b  = bf / F;
    const int f  = bf - b * F;

    const float a   = sigmoidf_(alpha[f]);
    const float oma = 1.0f - a;

    const float* p = mag + ((size_t)b * T + (size_t)c * L) * F + f;

    float m[L];
#pragma unroll
    for (int t = 0; t < L; ++t)
        m[t] = p[(size_t)t * F];
    asm volatile("" ::: "memory");

    float local = 0.0f;
#pragma unroll
    for (int t = 0; t < L; ++t)
        local = local * oma + (m[t] * m[t]) * a;
    S[(size_t)c * BF + bf] = local;
}

template <int L>
__global__ __launch_bounds__(256)
void fns11_emit(const float* __restrict__ mag,
                const float* __restrict__ s0,
                const float* __restrict__ weights,
                const float* __restrict__ bias,
                const float* __restrict__ alpha,
                const float* __restrict__ S,
                float* __restrict__ out,
                int B, int T, int F, int C) {
    const int BF = B * F;
    int g = blockIdx.x * blockDim.x + threadIdx.x;
    if (g >= BF * C) return;
    const int bf = g % BF;
    const int c  = g / BF;
    const int b  = bf / F;
    const int f  = bf - b * F;

    const float a   = sigmoidf_(alpha[f]);
    const float oma = 1.0f - a;
    const float w   = weights[f];
    const float bi  = bias[f];

    float carry = s0[bf];
    if (c > 0) {
        float D = 1.0f;
#pragma unroll
        for (int i = 0; i < L; ++i) D *= oma;
        for (int j = 0; j < c; ++j)
            carry = carry * D + S[(size_t)j * BF + bf];
    }

    const float* p = mag + ((size_t)b * T + (size_t)c * L) * F + f;
    float*       o = out + ((size_t)b * T + (size_t)c * L) * F + f;

    float m[L];
#pragma unroll
    for (int t = 0; t < L; ++t)
        m[t] = p[(size_t)t * F];
    asm volatile("" ::: "memory");

#pragma unroll
    for (int t = 0; t < L; ++t) {
        carry = carry * oma + (m[t] * m[t]) * a;
        o[(size_t)t * F] = m[t] * __builtin_amdgcn_rcpf(sqrtf(carry) + EPS) * w + bi;
    }
}

__global__ void fns_fallback(const float* __restrict__ mag,
                             const float* __restrict__ s0,
                             const float* __restrict__ weights,
                             const float* __restrict__ bias,
                             const float* __restrict__ alpha,
                             float* __restrict__ out,
                             int B, int T, int F) {
    int bf = blockIdx.x * blockDim.x + threadIdx.x;
    int BF = B * F;
    if (bf >= BF) return;
    int b = bf / F;
    int f = bf - b * F;

    float a  = sigmoidf_(alpha[f]);
    float w  = weights[f];
    float bi = bias[f];

    float carry = s0[bf];
    const float* p = mag + (size_t)b * T * F + f;
    float*       o = out + (size_t)b * T * F + f;

    for (int t = 0; t < T; ++t) {
        float m = p[(size_t)t * F];
        carry = carry * (1.0f - a) + (m * m) * a;
        o[(size_t)t * F] = m / (sqrtf(carry) + EPS) * w + bi;
    }
}

extern "C" void kernel_launch(void* const* d_in, const int* in_sizes, int n_in,
                              void* d_out, int out_size, void* d_ws, size_t ws_size,
                              hipStream_t stream) {
    const float* mag     = (const float*)d_in[0];
    const float* s0      = (const float*)d_in[1];
    const float* weights = (const float*)d_in[2];
    const float* bias    = (const float*)d_in[3];
    const float* alpha   = (const float*)d_in[4];
    float* out = (float*)d_out;

    int F  = in_sizes[4];          // alpha is [1, F]
    int BF = in_sizes[1];          // s is [B, F]
    int B  = BF / F;
    int T  = in_sizes[0] / BF;     // mag is [B, T, F]

    // ---- primary: fused single kernel (T==1000 shape) ----
    constexpr int CPB = 16;        // chains per block
    constexpr int LF  = 25;        // chunk length (fused)
    constexpr int CF  = 40;        // chunks (= T/LF)
    if (T == LF * CF && BF % CPB == 0) {
        int blocks = BF / CPB;     // 1028
        fns14_fused<CPB, LF, CF><<<blocks, CPB * CF, 0, stream>>>(
            mag, s0, weights, bias, alpha, out, B, T, F);
        return;
    }

    // ---- fallback 1: proven R12 two-kernel path ----
    constexpr int L = 50;
    if (T % L == 0) {
        int C  = T / L;
        int C1 = C - 1;
        size_t need = (size_t)C1 * BF * sizeof(float);
        if (C1 >= 1 && ws_size >= need) {
            float* S = (float*)d_ws;
            int n1 = BF * C1;
            int n2 = BF * C;
            fns12_aggregate<L><<<(n1 + 255) / 256, 256, 0, stream>>>(
                mag, alpha, S, B, T, F, C1);
            fns11_emit<L><<<(n2 + 255) / 256, 256, 0, stream>>>(
                mag, s0, weights, bias, alpha, S, out, B, T, F, C);
            return;
        }
    }

    // ---- fallback 2: generic ----
    int threads = 256;
    int blocks  = (BF + threads - 1) / threads;
    fns_fallback<<<blocks, threads, 0, stream>>>(mag, s0, weights, bias,
                                                 alpha, out, B, T, F);
}

// Round 15
// 52.853 us; speedup vs baseline: 1.2425x; 1.2425x over previous
//
#include <hip/hip_runtime.h>

#define EPS 1e-8f

__device__ __forceinline__ float sigmoidf_(float x) {
    return 1.0f / (1.0f + expf(-x));
}

// ---------------------------------------------------------------------------
// Single-kernel fused chunked scan, block-local carry exchange, LINE-ALIGNED.
// Block = CH(=32) chains x C(=32) chunks of L(=32): 1024 threads, 16 waves.
// Each half-wave accesses 32 consecutive floats = 128 B = one full cache
// line (R14's CPB=16 gave 64 B half-lines -> 1.4x fetch/write amplification).
//   phase A: deep-prefetch own chunk into m[L] (pinned), zero-carry scan,
//            aggregate -> LDS agg[C][CH].       (one __syncthreads)
//   phase B: Horner carry-in from s0 + agg[0..chunk) (predicated, uniform
//            D=(1-a)^L valid: chunks 0..C-2 full, ragged last chunk's
//            aggregate never consumed), re-scan from REGISTERS, store.
// mag read once, out written once -> compulsory 132 MB HBM only.
// ---------------------------------------------------------------------------

template <int CH, int L, int C>
__global__ __launch_bounds__(CH * C)
void fns15_fused(const float* __restrict__ mag,
                 const float* __restrict__ s0,
                 const float* __restrict__ weights,
                 const float* __restrict__ bias,
                 const float* __restrict__ alpha,
                 float* __restrict__ out,
                 int B, int T, int F) {
    __shared__ float agg[C][CH];

    const int chainL = threadIdx.x & (CH - 1);   // chain within block
    const int chunk  = threadIdx.x / CH;         // time chunk
    const int bf = blockIdx.x * CH + chainL;     // BF % CH == 0 (host-checked)
    const int b  = bf / F;
    const int f  = bf - b * F;

    const int t0  = chunk * L;
    const int cnt = min(L, T - t0);              // ragged last chunk

    const float a   = sigmoidf_(alpha[f]);
    const float oma = 1.0f - a;

    const float* p = mag + ((size_t)b * T + t0) * F + f;

    // ---- phase A: deep prefetch (predicated) + zero-carry local scan ----
    float m[L];
#pragma unroll
    for (int t = 0; t < L; ++t)
        m[t] = (t < cnt) ? p[(size_t)t * F] : 0.0f;
    asm volatile("" ::: "memory");   // pin loads: all in flight

    float local = 0.0f;
#pragma unroll
    for (int t = 0; t < L; ++t)
        local = local * oma + (m[t] * m[t]) * a;   // exact reference form

    agg[chunk][chainL] = local;
    __syncthreads();

    // ---- phase B: carry-in via Horner over LDS aggregates ----
    float D = 1.0f;                  // (1-a)^L via product
#pragma unroll
    for (int i = 0; i < L; ++i) D *= oma;

    float carry = s0[bf];
#pragma unroll
    for (int j = 0; j < C - 1; ++j) {
        float Sv = agg[j][chainL];   // 2 lanes/bank alias = free broadcast
        carry = (j < chunk) ? (carry * D + Sv) : carry;
    }

    const float w  = weights[f];
    const float bi = bias[f];
    float* o = out + ((size_t)b * T + t0) * F + f;

    // ---- re-scan from registers + normalize + store ----
#pragma unroll
    for (int t = 0; t < L; ++t) {
        carry = carry * oma + (m[t] * m[t]) * a;
        // 1/(sqrt+eps) via hw rcp (~1 ulp); bounded output -> abs err ~1e-6
        float r = m[t] * __builtin_amdgcn_rcpf(sqrtf(carry) + EPS) * w + bi;
        if (t < cnt)
            o[(size_t)t * F] = r;
    }
}

// ---------------------------------------------------------------------------
// Proven R12 two-kernel path (fallback for other shapes).
// ---------------------------------------------------------------------------

template <int L>
__global__ __launch_bounds__(256)
void fns12_aggregate(const float* __restrict__ mag,
                     const float* __restrict__ alpha,
                     float* __restrict__ S,   // [C-1][BF]
                     int B, int T, int F, int C1) {
    const int BF = B * F;
    int g = blockIdx.x * blockDim.x + threadIdx.x;
    if (g >= BF * C1) return;
    const int bf = g % BF;
    const int c  = g / BF;
    const int b  = bf / F;
    const int f  = bf - b * F;

    const float a   = sigmoidf_(alpha[f]);
    const float oma = 1.0f - a;

    const float* p = mag + ((size_t)b * T + (size_t)c * L) * F + f;

    float m[L];
#pragma unroll
    for (int t = 0; t < L; ++t)
        m[t] = p[(size_t)t * F];
    asm volatile("" ::: "memory");

    float local = 0.0f;
#pragma unroll
    for (int t = 0; t < L; ++t)
        local = local * oma + (m[t] * m[t]) * a;
    S[(size_t)c * BF + bf] = local;
}

template <int L>
__global__ __launch_bounds__(256)
void fns11_emit(const float* __restrict__ mag,
                const float* __restrict__ s0,
                const float* __restrict__ weights,
                const float* __restrict__ bias,
                const float* __restrict__ alpha,
                const float* __restrict__ S,
                float* __restrict__ out,
                int B, int T, int F, int C) {
    const int BF = B * F;
    int g = blockIdx.x * blockDim.x + threadIdx.x;
    if (g >= BF * C) return;
    const int bf = g % BF;
    const int c  = g / BF;
    const int b  = bf / F;
    const int f  = bf - b * F;

    const float a   = sigmoidf_(alpha[f]);
    const float oma = 1.0f - a;
    const float w   = weights[f];
    const float bi  = bias[f];

    float carry = s0[bf];
    if (c > 0) {
        float D = 1.0f;
#pragma unroll
        for (int i = 0; i < L; ++i) D *= oma;
        for (int j = 0; j < c; ++j)
            carry = carry * D + S[(size_t)j * BF + bf];
    }

    const float* p = mag + ((size_t)b * T + (size_t)c * L) * F + f;
    float*       o = out + ((size_t)b * T + (size_t)c * L) * F + f;

    float m[L];
#pragma unroll
    for (int t = 0; t < L; ++t)
        m[t] = p[(size_t)t * F];
    asm volatile("" ::: "memory");

#pragma unroll
    for (int t = 0; t < L; ++t) {
        carry = carry * oma + (m[t] * m[t]) * a;
        o[(size_t)t * F] = m[t] * __builtin_amdgcn_rcpf(sqrtf(carry) + EPS) * w + bi;
    }
}

__global__ void fns_fallback(const float* __restrict__ mag,
                             const float* __restrict__ s0,
                             const float* __restrict__ weights,
                             const float* __restrict__ bias,
                             const float* __restrict__ alpha,
                             float* __restrict__ out,
                             int B, int T, int F) {
    int bf = blockIdx.x * blockDim.x + threadIdx.x;
    int BF = B * F;
    if (bf >= BF) return;
    int b = bf / F;
    int f = bf - b * F;

    float a  = sigmoidf_(alpha[f]);
    float w  = weights[f];
    float bi = bias[f];

    float carry = s0[bf];
    const float* p = mag + (size_t)b * T * F + f;
    float*       o = out + (size_t)b * T * F + f;

    for (int t = 0; t < T; ++t) {
        float m = p[(size_t)t * F];
        carry = carry * (1.0f - a) + (m * m) * a;
        o[(size_t)t * F] = m / (sqrtf(carry) + EPS) * w + bi;
    }
}

extern "C" void kernel_launch(void* const* d_in, const int* in_sizes, int n_in,
                              void* d_out, int out_size, void* d_ws, size_t ws_size,
                              hipStream_t stream) {
    const float* mag     = (const float*)d_in[0];
    const float* s0      = (const float*)d_in[1];
    const float* weights = (const float*)d_in[2];
    const float* bias    = (const float*)d_in[3];
    const float* alpha   = (const float*)d_in[4];
    float* out = (float*)d_out;

    int F  = in_sizes[4];          // alpha is [1, F]
    int BF = in_sizes[1];          // s is [B, F]
    int B  = BF / F;
    int T  = in_sizes[0] / BF;     // mag is [B, T, F]

    // ---- primary: fused single kernel, line-aligned geometry ----
    constexpr int CH = 32;         // chains per block (half-wave = 128 B line)
    constexpr int LF = 32;         // chunk length
    constexpr int CF = 32;         // chunks; block = 1024 threads
    // need: chunks 0..CF-2 full (uniform D), last chunk non-empty, CH divides
    if ((CF - 1) * LF < T && T <= CF * LF && BF % CH == 0) {
        int blocks = BF / CH;      // 514
        fns15_fused<CH, LF, CF><<<blocks, CH * CF, 0, stream>>>(
            mag, s0, weights, bias, alpha, out, B, T, F);
        return;
    }

    // ---- fallback 1: proven R12 two-kernel path ----
    constexpr int L = 50;
    if (T % L == 0) {
        int C  = T / L;
        int C1 = C - 1;
        size_t need = (size_t)C1 * BF * sizeof(float);
        if (C1 >= 1 && ws_size >= need) {
            float* S = (float*)d_ws;
            int n1 = BF * C1;
            int n2 = BF * C;
            fns12_aggregate<L><<<(n1 + 255) / 256, 256, 0, stream>>>(
                mag, alpha, S, B, T, F, C1);
            fns11_emit<L><<<(n2 + 255) / 256, 256, 0, stream>>>(
                mag, s0, weights, bias, alpha, S, out, B, T, F, C);
            return;
        }
    }

    // ---- fallback 2: generic ----
    int threads = 256;
    int blocks  = (BF + threads - 1) / threads;
    fns_fallback<<<blocks, threads, 0, stream>>>(mag, s0, weights, bias,
                                                 alpha, out, B, T, F);
}

// Round 16
// 44.277 us; speedup vs baseline: 1.4832x; 1.1937x over previous
//
#include <hip/hip_runtime.h>

#define EPS 1e-8f

__device__ __forceinline__ float sigmoidf_(float x) {
    return 1.0f / (1.0f + expf(-x));
}

// ---------------------------------------------------------------------------
// Two-kernel chunked scan (proven R12 structure) with hierarchical carries:
// emit threads work at HALF-chunk granularity (L/2=25) for 2x thread count
// and <=64 VGPR (8 waves/SIMD), using S50 (full-chunk aggregates) + S25a
// (first-half aggregates) to reconstruct any sub-chunk carry with <=19
// parallel-prefetched loads + 1 predicated extra term.
//   k1  : thread (bf,c) c<20: m[50] deep prefetch; scan first 25 -> S25a[c],
//         continue to 50 -> S50[c] (c<19 only; S50[19] never consumed).
//   emit: thread (bf,sc) sc<40: c=sc/2. carry = Horner(s0, S50[0..c)) and,
//         if sc odd, carry = carry*D25 + S25a[c]. Then m[25] scan+store.
// All loads wave-coalesced (consecutive threads = consecutive bf).
// ---------------------------------------------------------------------------

template <int L, int LH>
__global__ __launch_bounds__(256)
void fns16_aggregate(const float* __restrict__ mag,
                     const float* __restrict__ alpha,
                     float* __restrict__ S50,    // [C-1][BF]
                     float* __restrict__ S25a,   // [C][BF]
                     int B, int T, int F, int C) {
    static_assert(L == 2 * LH, "");
    const int BF = B * F;
    int g = blockIdx.x * blockDim.x + threadIdx.x;
    if (g >= BF * C) return;
    const int bf = g % BF;
    const int c  = g / BF;
    const int b  = bf / F;
    const int f  = bf - b * F;

    const float a   = sigmoidf_(alpha[f]);
    const float oma = 1.0f - a;

    const float* p = mag + ((size_t)b * T + (size_t)c * L) * F + f;

    // deep prefetch: all L loads issued before the recurrence
    float m[L];
#pragma unroll
    for (int t = 0; t < L; ++t)
        m[t] = p[(size_t)t * F];
    asm volatile("" ::: "memory");

    float local = 0.0f;
#pragma unroll
    for (int t = 0; t < LH; ++t)
        local = local * oma + (m[t] * m[t]) * a;   // exact reference form
    S25a[(size_t)c * BF + bf] = local;             // first-half aggregate
#pragma unroll
    for (int t = LH; t < L; ++t)
        local = local * oma + (m[t] * m[t]) * a;
    if (c < C - 1)
        S50[(size_t)c * BF + bf] = local;          // full-chunk aggregate
}

template <int LH, int C>
__global__ __launch_bounds__(256)
void fns16_emit(const float* __restrict__ mag,
                const float* __restrict__ s0,
                const float* __restrict__ weights,
                const float* __restrict__ bias,
                const float* __restrict__ alpha,
                const float* __restrict__ S50,    // [C-1][BF]
                const float* __restrict__ S25a,   // [C][BF]
                float* __restrict__ out,
                int B, int T, int F) {
    const int BF = B * F;
    int g = blockIdx.x * blockDim.x + threadIdx.x;
    if (g >= BF * 2 * C) return;
    const int bf = g % BF;
    const int sc = g / BF;            // sub-chunk in [0, 2C)
    const int c   = sc >> 1;
    const int odd = sc & 1;
    const int b  = bf / F;
    const int f  = bf - b * F;

    const float a   = sigmoidf_(alpha[f]);
    const float oma = 1.0f - a;
    const float w   = weights[f];
    const float bi  = bias[f];

    const float* p = mag + ((size_t)b * T + (size_t)sc * LH) * F + f;
    float*       o = out + ((size_t)b * T + (size_t)sc * LH) * F + f;

    // ---- parallel prefetch: S50 chain terms (masked) + extra + mag ----
    float SS[C - 1];
#pragma unroll
    for (int j = 0; j < C - 1; ++j)
        SS[j] = (j < c) ? S50[(size_t)j * BF + bf] : 0.0f;
    float extra = odd ? S25a[(size_t)c * BF + bf] : 0.0f;

    float m[LH];
#pragma unroll
    for (int t = 0; t < LH; ++t)
        m[t] = p[(size_t)t * F];
    asm volatile("" ::: "memory");    // pin all loads: everything in flight

    // ---- carry combine: pure VALU (SS consumed -> registers freed) ----
    float D25 = 1.0f;                 // (1-a)^LH via product
#pragma unroll
    for (int i = 0; i < LH; ++i) D25 *= oma;
    const float D50 = D25 * D25;      // (1-a)^L

    float carry = s0[bf];
#pragma unroll
    for (int j = 0; j < C - 1; ++j)
        carry = (j < c) ? (carry * D50 + SS[j]) : carry;
    carry = odd ? (carry * D25 + extra) : carry;

    // ---- scan + normalize + store ----
#pragma unroll
    for (int t = 0; t < LH; ++t) {
        carry = carry * oma + (m[t] * m[t]) * a;
        // 1/(sqrt+eps) via hw rcp (~1 ulp); bounded output -> abs err ~1e-6
        o[(size_t)t * F] = m[t] * __builtin_amdgcn_rcpf(sqrtf(carry) + EPS) * w + bi;
    }
}

// ---------------------------------------------------------------------------
// Proven R12/R11 two-kernel path (fallback for other shapes).
// ---------------------------------------------------------------------------

template <int L>
__global__ __launch_bounds__(256)
void fns12_aggregate(const float* __restrict__ mag,
                     const float* __restrict__ alpha,
                     float* __restrict__ S,
                     int B, int T, int F, int C1) {
    const int BF = B * F;
    int g = blockIdx.x * blockDim.x + threadIdx.x;
    if (g >= BF * C1) return;
    const int bf = g % BF;
    const int c  = g / BF;
    const int b  = bf / F;
    const int f  = bf - b * F;

    const float a   = sigmoidf_(alpha[f]);
    const float oma = 1.0f - a;

    const float* p = mag + ((size_t)b * T + (size_t)c * L) * F + f;

    float m[L];
#pragma unroll
    for (int t = 0; t < L; ++t)
        m[t] = p[(size_t)t * F];
    asm volatile("" ::: "memory");

    float local = 0.0f;
#pragma unroll
    for (int t = 0; t < L; ++t)
        local = local * oma + (m[t] * m[t]) * a;
    S[(size_t)c * BF + bf] = local;
}

template <int L>
__global__ __launch_bounds__(256)
void fns11_emit(const float* __restrict__ mag,
                const float* __restrict__ s0,
                const float* __restrict__ weights,
                const float* __restrict__ bias,
                const float* __restrict__ alpha,
                const float* __restrict__ S,
                float* __restrict__ out,
                int B, int T, int F, int C) {
    const int BF = B * F;
    int g = blockIdx.x * blockDim.x + threadIdx.x;
    if (g >= BF * C) return;
    const int bf = g % BF;
    const int c  = g / BF;
    const int b  = bf / F;
    const int f  = bf - b * F;

    const float a   = sigmoidf_(alpha[f]);
    const float oma = 1.0f - a;
    const float w   = weights[f];
    const float bi  = bias[f];

    float carry = s0[bf];
    if (c > 0) {
        float D = 1.0f;
#pragma unroll
        for (int i = 0; i < L; ++i) D *= oma;
        for (int j = 0; j < c; ++j)
            carry = carry * D + S[(size_t)j * BF + bf];
    }

    const float* p = mag + ((size_t)b * T + (size_t)c * L) * F + f;
    float*       o = out + ((size_t)b * T + (size_t)c * L) * F + f;

    float m[L];
#pragma unroll
    for (int t = 0; t < L; ++t)
        m[t] = p[(size_t)t * F];
    asm volatile("" ::: "memory");

#pragma unroll
    for (int t = 0; t < L; ++t) {
        carry = carry * oma + (m[t] * m[t]) * a;
        o[(size_t)t * F] = m[t] * __builtin_amdgcn_rcpf(sqrtf(carry) + EPS) * w + bi;
    }
}

__global__ void fns_fallback(const float* __restrict__ mag,
                             const float* __restrict__ s0,
                             const float* __restrict__ weights,
                             const float* __restrict__ bias,
                             const float* __restrict__ alpha,
                             float* __restrict__ out,
                             int B, int T, int F) {
    int bf = blockIdx.x * blockDim.x + threadIdx.x;
    int BF = B * F;
    if (bf >= BF) return;
    int b = bf / F;
    int f = bf - b * F;

    float a  = sigmoidf_(alpha[f]);
    float w  = weights[f];
    float bi = bias[f];

    float carry = s0[bf];
    const float* p = mag + (size_t)b * T * F + f;
    float*       o = out + (size_t)b * T * F + f;

    for (int t = 0; t < T; ++t) {
        float m = p[(size_t)t * F];
        carry = carry * (1.0f - a) + (m * m) * a;
        o[(size_t)t * F] = m / (sqrtf(carry) + EPS) * w + bi;
    }
}

extern "C" void kernel_launch(void* const* d_in, const int* in_sizes, int n_in,
                              void* d_out, int out_size, void* d_ws, size_t ws_size,
                              hipStream_t stream) {
    const float* mag     = (const float*)d_in[0];
    const float* s0      = (const float*)d_in[1];
    const float* weights = (const float*)d_in[2];
    const float* bias    = (const float*)d_in[3];
    const float* alpha   = (const float*)d_in[4];
    float* out = (float*)d_out;

    int F  = in_sizes[4];          // alpha is [1, F]
    int BF = in_sizes[1];          // s is [B, F]
    int B  = BF / F;
    int T  = in_sizes[0] / BF;     // mag is [B, T, F]

    constexpr int L  = 50;         // chunk length
    constexpr int LH = 25;         // half-chunk (emit granularity)
    if (T % L == 0) {
        int C = T / L;             // 20 for T=1000
        if (C == 20) {
            size_t s50Bytes = (size_t)(C - 1) * BF * sizeof(float);
            size_t aOff     = (s50Bytes + 255) & ~(size_t)255;
            size_t need     = aOff + (size_t)C * BF * sizeof(float);
            if (ws_size >= need) {
                float* S50  = (float*)d_ws;
                float* S25a = (float*)((char*)d_ws + aOff);
                int n1 = BF * C;                 // 328,960 -> 1285 blocks
                int n2 = BF * 2 * C;             // 657,920 -> 2570 blocks
                fns16_aggregate<L, LH><<<(n1 + 255) / 256, 256, 0, stream>>>(
                    mag, alpha, S50, S25a, B, T, F, C);
                fns16_emit<LH, 20><<<(n2 + 255) / 256, 256, 0, stream>>>(
                    mag, s0, weights, bias, alpha, S50, S25a, out, B, T, F);
                return;
            }
        }
        // generic shapes: proven R12/R11 path
        int C1 = C - 1;
        size_t need = (size_t)C1 * BF * sizeof(float);
        if (C1 >= 1 && ws_size >= need) {
            float* S = (float*)d_ws;
            int n1 = BF * C1;
            int n2 = BF * C;
            fns12_aggregate<L><<<(n1 + 255) / 256, 256, 0, stream>>>(
                mag, alpha, S, B, T, F, C1);
            fns11_emit<L><<<(n2 + 255) / 256, 256, 0, stream>>>(
                mag, s0, weights, bias, alpha, S, out, B, T, F, C);
            return;
        }
    }

    int threads = 256;
    int blocks  = (BF + threads - 1) / threads;
    fns_fallback<<<blocks, threads, 0, stream>>>(mag, s0, weights, bias,
                                                 alpha, out, B, T, F);
}

// Round 17
// 42.231 us; speedup vs baseline: 1.5550x; 1.0484x over previous
//
#include <hip/hip_runtime.h>

#define EPS 1e-8f

__device__ __forceinline__ float sigmoidf_(float x) {
    return 1.0f / (1.0f + expf(-x));
}

// ---------------------------------------------------------------------------
// Two-kernel chunked scan (proven R12 structure) + L3-retention ordering:
// emit processes chunks in REVERSE order so its first-touched mag region is
// the one k1 read last (freshest in L3). R7/R8 counters showed emit re-fetch
// of 46.5/66 MB (30% evicted) with matching low-c-first order.
//   k1  : thread (bf,c): deep-prefetch m[50] (pinned), zero-carry scan,
//         store aggregate S[c][bf] (c < C-1; S[C-1] never consumed).
//   emit: thread (bf, C-1-rc): parallel-prefetch m[50] + masked SS[19],
//         Horner carry combine (pure VALU), scan + normalize + store.
// All loads wave-coalesced (consecutive threads = consecutive bf).
// ---------------------------------------------------------------------------

template <int L>
__global__ __launch_bounds__(256)
void fns17_aggregate(const float* __restrict__ mag,
                     const float* __restrict__ alpha,
                     float* __restrict__ S,   // [C-1][BF]
                     int B, int T, int F, int C1) {
    const int BF = B * F;
    int g = blockIdx.x * blockDim.x + threadIdx.x;
    if (g >= BF * C1) return;
    const int bf = g % BF;
    const int c  = g / BF;
    const int b  = bf / F;
    const int f  = bf - b * F;

    const float a   = sigmoidf_(alpha[f]);
    const float oma = 1.0f - a;

    const float* p = mag + ((size_t)b * T + (size_t)c * L) * F + f;

    // deep prefetch: all L loads issued before the recurrence
    float m[L];
#pragma unroll
    for (int t = 0; t < L; ++t)
        m[t] = p[(size_t)t * F];
    asm volatile("" ::: "memory");

    float local = 0.0f;
#pragma unroll
    for (int t = 0; t < L; ++t)
        local = local * oma + (m[t] * m[t]) * a;  // exact reference form
    S[(size_t)c * BF + bf] = local;
}

template <int L, int C>
__global__ __launch_bounds__(256)
void fns17_emit(const float* __restrict__ mag,
                const float* __restrict__ s0,
                const float* __restrict__ weights,
                const float* __restrict__ bias,
                const float* __restrict__ alpha,
                const float* __restrict__ S,   // [C-1][BF]
                float* __restrict__ out,
                int B, int T, int F) {
    const int BF = B * F;
    int g = blockIdx.x * blockDim.x + threadIdx.x;
    if (g >= BF * C) return;
    const int bf = g % BF;
    const int c  = C - 1 - (g / BF);   // REVERSED: freshest-in-L3 chunks first
    const int b  = bf / F;
    const int f  = bf - b * F;

    const float a   = sigmoidf_(alpha[f]);
    const float oma = 1.0f - a;
    const float w   = weights[f];
    const float bi  = bias[f];

    const float* p = mag + ((size_t)b * T + (size_t)c * L) * F + f;
    float*       o = out + ((size_t)b * T + (size_t)c * L) * F + f;

    // ---- deep prefetch 1: mag (HBM/L3, longest latency) ----
    float m[L];
#pragma unroll
    for (int t = 0; t < L; ++t)
        m[t] = p[(size_t)t * F];

    // ---- deep prefetch 2: chunk aggregates (L2-resident), masked ----
    float SS[C - 1];
#pragma unroll
    for (int j = 0; j < C - 1; ++j)
        SS[j] = (j < c) ? S[(size_t)j * BF + bf] : 0.0f;
    asm volatile("" ::: "memory");   // pin all loads before first use

    // ---- carry combine: pure VALU, identical arithmetic to sequential pass
    float D = 1.0f;                  // (1-a)^L via product
#pragma unroll
    for (int i = 0; i < L; ++i) D *= oma;
    float carry = s0[bf];
#pragma unroll
    for (int j = 0; j < C - 1; ++j)
        carry = (j < c) ? (carry * D + SS[j]) : carry;

    // ---- scan + normalize + store ----
#pragma unroll
    for (int t = 0; t < L; ++t) {
        carry = carry * oma + (m[t] * m[t]) * a;
        // 1/(sqrt+eps) via hw rcp (~1 ulp); bounded output -> abs err ~1e-6
        o[(size_t)t * F] = m[t] * __builtin_amdgcn_rcpf(sqrtf(carry) + EPS) * w + bi;
    }
}

// Generic emit (runtime C) -- proven R11 form, for non-standard shapes.
template <int L>
__global__ __launch_bounds__(256)
void fns11_emit(const float* __restrict__ mag,
                const float* __restrict__ s0,
                const float* __restrict__ weights,
                const float* __restrict__ bias,
                const float* __restrict__ alpha,
                const float* __restrict__ S,
                float* __restrict__ out,
                int B, int T, int F, int C) {
    const int BF = B * F;
    int g = blockIdx.x * blockDim.x + threadIdx.x;
    if (g >= BF * C) return;
    const int bf = g % BF;
    const int c  = g / BF;
    const int b  = bf / F;
    const int f  = bf - b * F;

    const float a   = sigmoidf_(alpha[f]);
    const float oma = 1.0f - a;
    const float w   = weights[f];
    const float bi  = bias[f];

    float carry = s0[bf];
    if (c > 0) {
        float D = 1.0f;
#pragma unroll
        for (int i = 0; i < L; ++i) D *= oma;
        for (int j = 0; j < c; ++j)
            carry = carry * D + S[(size_t)j * BF + bf];
    }

    const float* p = mag + ((size_t)b * T + (size_t)c * L) * F + f;
    float*       o = out + ((size_t)b * T + (size_t)c * L) * F + f;

    float m[L];
#pragma unroll
    for (int t = 0; t < L; ++t)
        m[t] = p[(size_t)t * F];
    asm volatile("" ::: "memory");

#pragma unroll
    for (int t = 0; t < L; ++t) {
        carry = carry * oma + (m[t] * m[t]) * a;
        o[(size_t)t * F] = m[t] * __builtin_amdgcn_rcpf(sqrtf(carry) + EPS) * w + bi;
    }
}

__global__ void fns_fallback(const float* __restrict__ mag,
                             const float* __restrict__ s0,
                             const float* __restrict__ weights,
                             const float* __restrict__ bias,
                             const float* __restrict__ alpha,
                             float* __restrict__ out,
                             int B, int T, int F) {
    int bf = blockIdx.x * blockDim.x + threadIdx.x;
    int BF = B * F;
    if (bf >= BF) return;
    int b = bf / F;
    int f = bf - b * F;

    float a  = sigmoidf_(alpha[f]);
    float w  = weights[f];
    float bi = bias[f];

    float carry = s0[bf];
    const float* p = mag + (size_t)b * T * F + f;
    float*       o = out + (size_t)b * T * F + f;

    for (int t = 0; t < T; ++t) {
        float m = p[(size_t)t * F];
        carry = carry * (1.0f - a) + (m * m) * a;
        o[(size_t)t * F] = m / (sqrtf(carry) + EPS) * w + bi;
    }
}

extern "C" void kernel_launch(void* const* d_in, const int* in_sizes, int n_in,
                              void* d_out, int out_size, void* d_ws, size_t ws_size,
                              hipStream_t stream) {
    const float* mag     = (const float*)d_in[0];
    const float* s0      = (const float*)d_in[1];
    const float* weights = (const float*)d_in[2];
    const float* bias    = (const float*)d_in[3];
    const float* alpha   = (const float*)d_in[4];
    float* out = (float*)d_out;

    int F  = in_sizes[4];          // alpha is [1, F]
    int BF = in_sizes[1];          // s is [B, F]
    int B  = BF / F;
    int T  = in_sizes[0] / BF;     // mag is [B, T, F]

    constexpr int L = 50;          // chunk length (compile-time, full unroll)
    if (T % L == 0) {
        int C  = T / L;            // 20 for T=1000
        int C1 = C - 1;
        size_t need = (size_t)C1 * BF * sizeof(float);
        if (C1 >= 1 && ws_size >= need) {
            float* S = (float*)d_ws;
            int n1 = BF * C1;                    // 312,512
            int n2 = BF * C;                     // 328,960
            fns17_aggregate<L><<<(n1 + 255) / 256, 256, 0, stream>>>(
                mag, alpha, S, B, T, F, C1);
            if (C == 20) {
                fns17_emit<L, 20><<<(n2 + 255) / 256, 256, 0, stream>>>(
                    mag, s0, weights, bias, alpha, S, out, B, T, F);
            } else {
                fns11_emit<L><<<(n2 + 255) / 256, 256, 0, stream>>>(
                    mag, s0, weights, bias, alpha, S, out, B, T, F, C);
            }
            return;
        }
    }

    int threads = 256;
    int blocks  = (BF + threads - 1) / threads;
    fns_fallback<<<blocks, threads, 0, stream>>>(mag, s0, weights, bias,
                                                 alpha, out, B, T, F);
}